// Round 17
// baseline (82.083 us; speedup 1.0000x reference)
//
#include <hip/hip_runtime.h>
#include <math.h>

// Problem constants
#define BATCH 64
#define HH 512
#define WW 512
#define PAD 15
#define NELEM ((size_t)BATCH * HH * WW)
#define INV_KK (1.0f / 961.0f)

#define TILE_H 32              // rows per block
#define NIT (TILE_H / 4)       // 8
#define BPI (HH / TILE_H)      // 16 blocks per image
#define NBLK (BATCH * BPI)     // 1024 blocks -> 4 blocks/CU
#define NXCD 8

typedef float f4 __attribute__((ext_vector_type(4)));

__device__ __forceinline__ float wave_reduce(float v) {
    #pragma unroll
    for (int off = 32; off; off >>= 1) v += __shfl_down(v, off, 64);
    return v;
}

// ---------------------------------------------------------------------------
// Wave64 inclusive add-scan via DPP (gfx9/CDNA rocPRIM sequence): VALU-only,
// replaces the ds_bpermute __shfl_up chain (R16: 51.5 -> 49.5us).
// ---------------------------------------------------------------------------
__device__ __forceinline__ float dpp_scan_incl(float x) {
    float v = x;
    int t;
    t = __builtin_amdgcn_update_dpp(0, __float_as_int(v), 0x111, 0xf, 0xf, true); // row_shr:1
    v += __int_as_float(t);
    t = __builtin_amdgcn_update_dpp(0, __float_as_int(v), 0x112, 0xf, 0xf, true); // row_shr:2
    v += __int_as_float(t);
    t = __builtin_amdgcn_update_dpp(0, __float_as_int(v), 0x114, 0xf, 0xf, true); // row_shr:4
    v += __int_as_float(t);
    t = __builtin_amdgcn_update_dpp(0, __float_as_int(v), 0x118, 0xf, 0xf, true); // row_shr:8
    v += __int_as_float(t);
    t = __builtin_amdgcn_update_dpp(0, __float_as_int(v), 0x142, 0xa, 0xf, true); // row_bcast15 -> rows 1,3
    v += __int_as_float(t);
    t = __builtin_amdgcn_update_dpp(0, __float_as_int(v), 0x143, 0xc, 0xf, true); // row_bcast31 -> rows 2,3
    v += __int_as_float(t);
    return v;
}

// ---------------------------------------------------------------------------
// R16 champion structure (49.5us), ONE isolated change: finalize is fused in
// via the last-block-done ticket (hipCUB DeviceReduce pattern) — removes the
// second kernel launch. Writers: plain partials stores + __threadfence
// (release, buffer_wbl2 sc1) + device-scope atomicAdd ticket. The last block
// re-fences (acquire, buffer_inv sc1 — clears stale per-XCD L2 lines from
// the previous graph replay) and reduces the 24KB partials itself.
// ---------------------------------------------------------------------------
__global__ __launch_bounds__(256) void fused_kernel(const float* __restrict__ pred,
                                                    const float* __restrict__ mask,
                                                    double* __restrict__ partials,
                                                    unsigned int* __restrict__ counter,
                                                    float* __restrict__ out) {
    __shared__ float vrow[2][4][WW];   // double-buffered vertical-sum rows
    __shared__ float P[4][WW];         // per-wave private prefix rows
    __shared__ float red[3][4];
    __shared__ int isLast;

    // XCD swizzle: xcd = f%8 (HW round-robin); each XCD owns 8 whole images.
    const int f    = blockIdx.x;
    const int xcd  = f & (NXCD - 1);
    const int slot = f >> 3;               // 0..127
    const int img  = xcd * 8 + (slot >> 4);
    const int tile = slot & (BPI - 1);

    const int tid  = threadIdx.x;
    const int lane = tid & 63;
    const int wv   = tid >> 6;
    const int h0   = tile * TILE_H;        // block's first output row (max 480)
    const int c0   = tid;                  // producer columns
    const int c1   = tid + 256;

    const float* mb = mask + (size_t)img * HH * WW;
    const float* pb = pred + (size_t)img * HH * WW;

    // --- init rolling vertical window for row h0: rows [max(0,h0-15), min(511,h0+15)]
    float r0 = 0.0f, r1 = 0.0f;
    {
        int lo = h0 - PAD; if (lo < 0) lo = 0;
        int hi = h0 + PAD; if (hi > HH - 1) hi = HH - 1;
        for (int y = lo; y <= hi; ++y) {
            r0 += mb[(size_t)y * WW + c0];
            r1 += mb[(size_t)y * WW + c1];
        }
    }

    // Prefetched add/sub rows for the upcoming iteration (rows h+16 / h-15
    // for h = hbase..hbase+3). 16 named registers.
    float pa0, pa1, pa2, pa3, ps0, ps1, ps2, ps3;   // column c0
    float qa0, qa1, qa2, qa3, qs0, qs1, qs2, qs3;   // column c1

    #define PREFETCH(ii)                                                       \
    {                                                                          \
        const int hb = h0 + 4 * (ii);                                          \
        const int a0r = hb + 16, a1r = hb + 17, a2r = hb + 18, a3r = hb + 19;  \
        const int s0r = hb - 15, s1r = hb - 14, s2r = hb - 13, s3r = hb - 12;  \
        pa0 = (a0r < HH) ? mb[(size_t)a0r * WW + c0] : 0.0f;                   \
        pa1 = (a1r < HH) ? mb[(size_t)a1r * WW + c0] : 0.0f;                   \
        pa2 = (a2r < HH) ? mb[(size_t)a2r * WW + c0] : 0.0f;                   \
        pa3 = (a3r < HH) ? mb[(size_t)a3r * WW + c0] : 0.0f;                   \
        ps0 = (s0r >= 0) ? mb[(size_t)s0r * WW + c0] : 0.0f;                   \
        ps1 = (s1r >= 0) ? mb[(size_t)s1r * WW + c0] : 0.0f;                   \
        ps2 = (s2r >= 0) ? mb[(size_t)s2r * WW + c0] : 0.0f;                   \
        ps3 = (s3r >= 0) ? mb[(size_t)s3r * WW + c0] : 0.0f;                   \
        qa0 = (a0r < HH) ? mb[(size_t)a0r * WW + c1] : 0.0f;                   \
        qa1 = (a1r < HH) ? mb[(size_t)a1r * WW + c1] : 0.0f;                   \
        qa2 = (a2r < HH) ? mb[(size_t)a2r * WW + c1] : 0.0f;                   \
        qa3 = (a3r < HH) ? mb[(size_t)a3r * WW + c1] : 0.0f;                   \
        qs0 = (s0r >= 0) ? mb[(size_t)s0r * WW + c1] : 0.0f;                   \
        qs1 = (s1r >= 0) ? mb[(size_t)s1r * WW + c1] : 0.0f;                   \
        qs2 = (s2r >= 0) ? mb[(size_t)s2r * WW + c1] : 0.0f;                   \
        qs3 = (s3r >= 0) ? mb[(size_t)s3r * WW + c1] : 0.0f;                   \
    }

    PREFETCH(0)

    float accb = 0.0f, acci = 0.0f, accu = 0.0f;

    #pragma unroll 1   // forbid outer unroll: protects the register budget
    for (int it = 0; it < NIT; ++it) {
        const int hbase = h0 + it * 4;
        float (*vb)[WW] = vrow[it & 1];

        // --- producer: pure LDS/VALU, consumes prefetched rows ---
        vb[0][c0] = r0; vb[0][c1] = r1; r0 += pa0 - ps0; r1 += qa0 - qs0;
        vb[1][c0] = r0; vb[1][c1] = r1; r0 += pa1 - ps1; r1 += qa1 - qs1;
        vb[2][c0] = r0; vb[2][c1] = r1; r0 += pa2 - ps2; r1 += qa2 - qs2;
        vb[3][c0] = r0; vb[3][c1] = r1; r0 += pa3 - ps3; r1 += qa3 - qs3;
        __syncthreads();   // vb visible to all waves (the only barrier)

        // --- issue next iteration's loads; latency hides under scan+loss ---
        if (it + 1 < NIT) PREFETCH(it + 1)

        // --- scan: wave wv prefix-scans vb[wv] into P[wv] (wave-private) ---
        const int h = hbase + wv;
        const size_t rbase = (size_t)h * WW;

        f4 va = *(const f4*)&vb[wv][8 * lane];
        f4 vbv = *(const f4*)&vb[wv][8 * lane + 4];
        float p0 = va.x;
        float p1 = p0 + va.y;
        float p2 = p1 + va.z;
        float p3 = p2 + va.w;
        float p4 = p3 + vbv.x;
        float p5 = p4 + vbv.y;
        float p6 = p5 + vbv.z;
        float p7 = p6 + vbv.w;
        const float lanesum = p7;
        const float incl = dpp_scan_incl(lanesum);   // DPP scan (R16)
        const float excl = incl - lanesum;
        f4 Pa, Pb;
        Pa.x = excl + p0; Pa.y = excl + p1; Pa.z = excl + p2; Pa.w = excl + p3;
        Pb.x = excl + p4; Pb.y = excl + p5; Pb.z = excl + p6; Pb.w = excl + p7;
        *(f4*)&P[wv][8 * lane]     = Pa;
        *(f4*)&P[wv][8 * lane + 4] = Pb;
        // no barrier: P[wv] is wave-private (same-wave DS ordering).

        // --- loss: lane owns w = lane + 64k of row hbase+wv ---
        #pragma unroll
        for (int k = 0; k < 8; ++k) {
            const int w = lane + 64 * k;
            int hiw = w + PAD; if (hiw > WW - 1) hiw = WW - 1;
            float s = P[wv][hiw];
            if (w >= PAD + 1) s -= P[wv][w - PAD - 1];

            const float m  = mb[rbase + w];
            const float pr = pb[rbase + w];

            const float weit = 1.0f + 5.0f * fabsf(s * INV_KK - m);
            const float e    = __expf(-fabsf(pr));
            const float bce  = fmaxf(pr, 0.0f) - pr * m + __logf(1.0f + e);
            const float inv  = __builtin_amdgcn_rcpf(1.0f + e);
            const float p    = (pr >= 0.0f) ? inv : e * inv;   // sigmoid(pr)

            accb += bce;
            acci += p * m * weit;
            accu += (p + m) * weit;
        }
        // no end barrier: vrow is double-buffered (R11 safety argument).
    }
    #undef PREFETCH

    // --- block reduction ---
    accb = wave_reduce(accb);
    acci = wave_reduce(acci);
    accu = wave_reduce(accu);
    if (lane == 0) { red[0][wv] = accb; red[1][wv] = acci; red[2][wv] = accu; }
    __syncthreads();
    if (tid == 0) {
        double bt = (double)red[0][0] + red[0][1] + red[0][2] + red[0][3];
        double it2 = (double)red[1][0] + red[1][1] + red[1][2] + red[1][3];
        double ut = (double)red[2][0] + red[2][1] + red[2][2] + red[2][3];
        const size_t pidx = (size_t)img * BPI + tile;   // un-swizzled index
        partials[pidx * 3 + 0] = bt;
        partials[pidx * 3 + 1] = it2;
        partials[pidx * 3 + 2] = ut;
        __threadfence();                                  // release partials
        unsigned int ticket = atomicAdd(counter, 1u);     // device-scope
        isLast = (ticket == NBLK - 1);
    }
    __syncthreads();

    // --- last block performs the finalize (no second kernel) ---
    if (isLast) {
        __threadfence();   // acquire: invalidate stale L2 lines (prev replay)
        __shared__ double redbce[4];

        double bsum = 0.0;
        for (int i = tid; i < NBLK; i += 256) bsum += partials[(size_t)i * 3 + 0];
        #pragma unroll
        for (int off = 32; off; off >>= 1) bsum += __shfl_down(bsum, off, 64);
        if (lane == 0) redbce[wv] = bsum;
        __syncthreads();

        double wiou_term = 0.0;
        if (tid < 64) {
            int bb = tid;
            double it = 0.0, ut = 0.0;
            for (int j = 0; j < BPI; ++j) {
                it += partials[(size_t)(bb * BPI + j) * 3 + 1];
                ut += partials[(size_t)(bb * BPI + j) * 3 + 2];
            }
            wiou_term = 1.0 - (it + 1.0) / (ut - it + 1.0);
        }
        if (wv == 0) {
            #pragma unroll
            for (int off = 32; off; off >>= 1) wiou_term += __shfl_down(wiou_term, off, 64);
        }
        if (tid == 0) {
            double wbce = (redbce[0] + redbce[1] + redbce[2] + redbce[3]) / (double)NELEM;
            out[0] = (float)(wbce + wiou_term * (1.0 / 64.0));
        }
    }
}

// ---------------------------------------------------------------------------
// Fallback path (tiny ws): recompute vertical sums in-kernel + atomics.
// ---------------------------------------------------------------------------
#define ACC_DOUBLES 129
__global__ __launch_bounds__(256) void rowpass_nows_kernel(const float* __restrict__ pred,
                                                           const float* __restrict__ mask,
                                                           double* __restrict__ acc) {
    __shared__ float vrow1[WW];
    __shared__ float red[3][4];
    int b = blockIdx.x / HH;
    int h = blockIdx.x % HH;
    int lo = h - PAD; if (lo < 0) lo = 0;
    int hi = h + PAD; if (hi > HH - 1) hi = HH - 1;
    float s0 = 0.0f, s1 = 0.0f;
    const float* mb = mask + (size_t)b * HH * WW;
    for (int y = lo; y <= hi; ++y) {
        s0 += mb[(size_t)y * WW + threadIdx.x];
        s1 += mb[(size_t)y * WW + threadIdx.x + 256];
    }
    vrow1[threadIdx.x]       = s0;
    vrow1[threadIdx.x + 256] = s1;
    __syncthreads();

    size_t base = ((size_t)b * HH + h) * WW;
    float bce_p = 0.0f, inter_p = 0.0f, uni_p = 0.0f;
    for (int w = threadIdx.x; w < WW; w += 256) {
        int wlo = w - PAD; if (wlo < 0) wlo = 0;
        int whi = w + PAD; if (whi > WW - 1) whi = WW - 1;
        float s = 0.0f;
        for (int k = wlo; k <= whi; ++k) s += vrow1[k];
        float m  = mask[base + w];
        float pr = pred[base + w];
        float weit = 1.0f + 5.0f * fabsf(s * INV_KK - m);
        float e   = expf(-fabsf(pr));
        float bce = fmaxf(pr, 0.0f) - pr * m + log1pf(e);
        float inv = 1.0f / (1.0f + e);
        float p   = (pr >= 0.0f) ? inv : e * inv;
        bce_p += bce; inter_p += p * m * weit; uni_p += (p + m) * weit;
    }
    int lane = threadIdx.x & 63, wvv = threadIdx.x >> 6;
    bce_p = wave_reduce(bce_p); inter_p = wave_reduce(inter_p); uni_p = wave_reduce(uni_p);
    if (lane == 0) { red[0][wvv] = bce_p; red[1][wvv] = inter_p; red[2][wvv] = uni_p; }
    __syncthreads();
    if (threadIdx.x == 0) {
        atomicAdd(&acc[0], (double)(red[0][0] + red[0][1] + red[0][2] + red[0][3]));
        atomicAdd(&acc[1 + b], (double)(red[1][0] + red[1][1] + red[1][2] + red[1][3]));
        atomicAdd(&acc[65 + b], (double)(red[2][0] + red[2][1] + red[2][2] + red[2][3]));
    }
}

__global__ void finalize_atomic_kernel(const double* __restrict__ acc, float* __restrict__ out) {
    int b = threadIdx.x;
    double inter = acc[1 + b];
    double uni   = acc[65 + b];
    double wiou = 1.0 - (inter + 1.0) / (uni - inter + 1.0);
    #pragma unroll
    for (int off = 32; off; off >>= 1) wiou += __shfl_down(wiou, off, 64);
    if (b == 0) {
        double wbce = acc[0] / (double)NELEM;
        out[0] = (float)(wbce + wiou * (1.0 / 64.0));
    }
}

// ---------------------------------------------------------------------------
extern "C" void kernel_launch(void* const* d_in, const int* in_sizes, int n_in,
                              void* d_out, int out_size, void* d_ws, size_t ws_size,
                              hipStream_t stream) {
    const float* pred = (const float*)d_in[0];
    const float* mask = (const float*)d_in[1];
    float* out = (float*)d_out;

    const size_t part_bytes = (size_t)NBLK * 3 * sizeof(double);   // 24 KiB
    const size_t need = part_bytes + sizeof(unsigned int);

    if (ws_size >= need) {
        double* partials = (double*)d_ws;
        unsigned int* counter = (unsigned int*)((char*)d_ws + part_bytes);
        hipMemsetAsync(counter, 0, sizeof(unsigned int), stream);
        fused_kernel<<<NBLK, 256, 0, stream>>>(pred, mask, partials, counter, out);
    } else {
        double* acc = (double*)d_ws;
        hipMemsetAsync(acc, 0, ACC_DOUBLES * sizeof(double), stream);
        rowpass_nows_kernel<<<BATCH * HH, 256, 0, stream>>>(pred, mask, acc);
        finalize_atomic_kernel<<<1, 64, 0, stream>>>(acc, out);
    }
}

// Round 18
// 51.612 us; speedup vs baseline: 1.5904x; 1.5904x over previous
//
#include <hip/hip_runtime.h>
#include <math.h>

// Problem constants
#define BATCH 64
#define HH 512
#define WW 512
#define PAD 15
#define NELEM ((size_t)BATCH * HH * WW)
#define INV_KK (1.0f / 961.0f)

#define TILE_H 32              // rows per block
#define NIT (TILE_H / 4)       // 8
#define BPI (HH / TILE_H)      // 16 blocks per image
#define NBLK (BATCH * BPI)     // 1024 blocks -> 4 blocks/CU
#define NXCD 8

typedef float f4 __attribute__((ext_vector_type(4)));

__device__ __forceinline__ float wave_reduce(float v) {
    #pragma unroll
    for (int off = 32; off; off >>= 1) v += __shfl_down(v, off, 64);
    return v;
}

// ---------------------------------------------------------------------------
// Wave64 inclusive add-scan via DPP (gfx9/CDNA rocPRIM sequence): VALU-only,
// replaces the ds_bpermute __shfl_up chain (R16: 51.5 -> 49.5us).
// ---------------------------------------------------------------------------
__device__ __forceinline__ float dpp_scan_incl(float x) {
    float v = x;
    int t;
    t = __builtin_amdgcn_update_dpp(0, __float_as_int(v), 0x111, 0xf, 0xf, true); // row_shr:1
    v += __int_as_float(t);
    t = __builtin_amdgcn_update_dpp(0, __float_as_int(v), 0x112, 0xf, 0xf, true); // row_shr:2
    v += __int_as_float(t);
    t = __builtin_amdgcn_update_dpp(0, __float_as_int(v), 0x114, 0xf, 0xf, true); // row_shr:4
    v += __int_as_float(t);
    t = __builtin_amdgcn_update_dpp(0, __float_as_int(v), 0x118, 0xf, 0xf, true); // row_shr:8
    v += __int_as_float(t);
    t = __builtin_amdgcn_update_dpp(0, __float_as_int(v), 0x142, 0xa, 0xf, true); // row_bcast15 -> rows 1,3
    v += __int_as_float(t);
    t = __builtin_amdgcn_update_dpp(0, __float_as_int(v), 0x143, 0xc, 0xf, true); // row_bcast31 -> rows 2,3
    v += __int_as_float(t);
    return v;
}

// ---------------------------------------------------------------------------
// CHAMPION (R16, 49.5us) — verbatim revert after R17's fence regression
// (per-block __threadfence release = buffer_wbl2 L2 writeback x1024 blocks,
// cost ~30us; the separate finalize launch is cheaper).
// Structure: R11 prefetch/double-buffer/1-barrier + DPP scan.
//  - prefetch: next iteration's add/sub mask rows in registers
//  - vrow double-buffered, 1 barrier per 4 rows
//  - wave-private P row, no scan->loss barrier
// ---------------------------------------------------------------------------
__global__ __launch_bounds__(256) void fused_kernel(const float* __restrict__ pred,
                                                    const float* __restrict__ mask,
                                                    double* __restrict__ partials) {
    __shared__ float vrow[2][4][WW];   // double-buffered vertical-sum rows
    __shared__ float P[4][WW];         // per-wave private prefix rows
    __shared__ float red[3][4];

    // XCD swizzle: xcd = f%8 (HW round-robin); each XCD owns 8 whole images.
    const int f    = blockIdx.x;
    const int xcd  = f & (NXCD - 1);
    const int slot = f >> 3;               // 0..127
    const int img  = xcd * 8 + (slot >> 4);
    const int tile = slot & (BPI - 1);

    const int tid  = threadIdx.x;
    const int lane = tid & 63;
    const int wv   = tid >> 6;
    const int h0   = tile * TILE_H;        // block's first output row (max 480)
    const int c0   = tid;                  // producer columns
    const int c1   = tid + 256;

    const float* mb = mask + (size_t)img * HH * WW;
    const float* pb = pred + (size_t)img * HH * WW;

    // --- init rolling vertical window for row h0: rows [max(0,h0-15), min(511,h0+15)]
    float r0 = 0.0f, r1 = 0.0f;
    {
        int lo = h0 - PAD; if (lo < 0) lo = 0;
        int hi = h0 + PAD; if (hi > HH - 1) hi = HH - 1;
        for (int y = lo; y <= hi; ++y) {
            r0 += mb[(size_t)y * WW + c0];
            r1 += mb[(size_t)y * WW + c1];
        }
    }

    // Prefetched add/sub rows for the upcoming iteration (rows h+16 / h-15
    // for h = hbase..hbase+3). 16 named registers.
    float pa0, pa1, pa2, pa3, ps0, ps1, ps2, ps3;   // column c0
    float qa0, qa1, qa2, qa3, qs0, qs1, qs2, qs3;   // column c1

    #define PREFETCH(ii)                                                       \
    {                                                                          \
        const int hb = h0 + 4 * (ii);                                          \
        const int a0r = hb + 16, a1r = hb + 17, a2r = hb + 18, a3r = hb + 19;  \
        const int s0r = hb - 15, s1r = hb - 14, s2r = hb - 13, s3r = hb - 12;  \
        pa0 = (a0r < HH) ? mb[(size_t)a0r * WW + c0] : 0.0f;                   \
        pa1 = (a1r < HH) ? mb[(size_t)a1r * WW + c0] : 0.0f;                   \
        pa2 = (a2r < HH) ? mb[(size_t)a2r * WW + c0] : 0.0f;                   \
        pa3 = (a3r < HH) ? mb[(size_t)a3r * WW + c0] : 0.0f;                   \
        ps0 = (s0r >= 0) ? mb[(size_t)s0r * WW + c0] : 0.0f;                   \
        ps1 = (s1r >= 0) ? mb[(size_t)s1r * WW + c0] : 0.0f;                   \
        ps2 = (s2r >= 0) ? mb[(size_t)s2r * WW + c0] : 0.0f;                   \
        ps3 = (s3r >= 0) ? mb[(size_t)s3r * WW + c0] : 0.0f;                   \
        qa0 = (a0r < HH) ? mb[(size_t)a0r * WW + c1] : 0.0f;                   \
        qa1 = (a1r < HH) ? mb[(size_t)a1r * WW + c1] : 0.0f;                   \
        qa2 = (a2r < HH) ? mb[(size_t)a2r * WW + c1] : 0.0f;                   \
        qa3 = (a3r < HH) ? mb[(size_t)a3r * WW + c1] : 0.0f;                   \
        qs0 = (s0r >= 0) ? mb[(size_t)s0r * WW + c1] : 0.0f;                   \
        qs1 = (s1r >= 0) ? mb[(size_t)s1r * WW + c1] : 0.0f;                   \
        qs2 = (s2r >= 0) ? mb[(size_t)s2r * WW + c1] : 0.0f;                   \
        qs3 = (s3r >= 0) ? mb[(size_t)s3r * WW + c1] : 0.0f;                   \
    }

    PREFETCH(0)

    float accb = 0.0f, acci = 0.0f, accu = 0.0f;

    #pragma unroll 1   // forbid outer unroll: protects the register budget
    for (int it = 0; it < NIT; ++it) {
        const int hbase = h0 + it * 4;
        float (*vb)[WW] = vrow[it & 1];

        // --- producer: pure LDS/VALU, consumes prefetched rows ---
        vb[0][c0] = r0; vb[0][c1] = r1; r0 += pa0 - ps0; r1 += qa0 - qs0;
        vb[1][c0] = r0; vb[1][c1] = r1; r0 += pa1 - ps1; r1 += qa1 - qs1;
        vb[2][c0] = r0; vb[2][c1] = r1; r0 += pa2 - ps2; r1 += qa2 - qs2;
        vb[3][c0] = r0; vb[3][c1] = r1; r0 += pa3 - ps3; r1 += qa3 - qs3;
        __syncthreads();   // vb visible to all waves (the only barrier)

        // --- issue next iteration's loads; latency hides under scan+loss ---
        if (it + 1 < NIT) PREFETCH(it + 1)

        // --- scan: wave wv prefix-scans vb[wv] into P[wv] (wave-private) ---
        const int h = hbase + wv;
        const size_t rbase = (size_t)h * WW;

        f4 va = *(const f4*)&vb[wv][8 * lane];
        f4 vbv = *(const f4*)&vb[wv][8 * lane + 4];
        float p0 = va.x;
        float p1 = p0 + va.y;
        float p2 = p1 + va.z;
        float p3 = p2 + va.w;
        float p4 = p3 + vbv.x;
        float p5 = p4 + vbv.y;
        float p6 = p5 + vbv.z;
        float p7 = p6 + vbv.w;
        const float lanesum = p7;
        const float incl = dpp_scan_incl(lanesum);   // DPP scan (R16)
        const float excl = incl - lanesum;
        f4 Pa, Pb;
        Pa.x = excl + p0; Pa.y = excl + p1; Pa.z = excl + p2; Pa.w = excl + p3;
        Pb.x = excl + p4; Pb.y = excl + p5; Pb.z = excl + p6; Pb.w = excl + p7;
        *(f4*)&P[wv][8 * lane]     = Pa;
        *(f4*)&P[wv][8 * lane + 4] = Pb;
        // no barrier: P[wv] is wave-private (same-wave DS ordering).

        // --- loss: lane owns w = lane + 64k of row hbase+wv ---
        #pragma unroll
        for (int k = 0; k < 8; ++k) {
            const int w = lane + 64 * k;
            int hiw = w + PAD; if (hiw > WW - 1) hiw = WW - 1;
            float s = P[wv][hiw];
            if (w >= PAD + 1) s -= P[wv][w - PAD - 1];

            const float m  = mb[rbase + w];
            const float pr = pb[rbase + w];

            const float weit = 1.0f + 5.0f * fabsf(s * INV_KK - m);
            const float e    = __expf(-fabsf(pr));
            const float bce  = fmaxf(pr, 0.0f) - pr * m + __logf(1.0f + e);
            const float inv  = __builtin_amdgcn_rcpf(1.0f + e);
            const float p    = (pr >= 0.0f) ? inv : e * inv;   // sigmoid(pr)

            accb += bce;
            acci += p * m * weit;
            accu += (p + m) * weit;
        }
        // no end barrier: vrow is double-buffered (R11 safety argument).
    }
    #undef PREFETCH

    // --- block reduction ---
    accb = wave_reduce(accb);
    acci = wave_reduce(acci);
    accu = wave_reduce(accu);
    if (lane == 0) { red[0][wv] = accb; red[1][wv] = acci; red[2][wv] = accu; }
    __syncthreads();
    if (tid == 0) {
        double bt = (double)red[0][0] + red[0][1] + red[0][2] + red[0][3];
        double it2 = (double)red[1][0] + red[1][1] + red[1][2] + red[1][3];
        double ut = (double)red[2][0] + red[2][1] + red[2][2] + red[2][3];
        const size_t pidx = (size_t)img * BPI + tile;   // un-swizzled index
        partials[pidx * 3 + 0] = bt;
        partials[pidx * 3 + 1] = it2;
        partials[pidx * 3 + 2] = ut;
    }
}

// ---------------------------------------------------------------------------
// Finalize from per-block partials (indexed img*BPI + tile), NBLK = 1024.
// ---------------------------------------------------------------------------
__global__ __launch_bounds__(256) void finalize_kernel(const double* __restrict__ partials,
                                                       float* __restrict__ out) {
    __shared__ double redbce[4];
    int tid = threadIdx.x, lane = tid & 63, wv = tid >> 6;

    double bsum = 0.0;
    for (int i = tid; i < NBLK; i += 256) bsum += partials[(size_t)i * 3 + 0];
    #pragma unroll
    for (int off = 32; off; off >>= 1) bsum += __shfl_down(bsum, off, 64);
    if (lane == 0) redbce[wv] = bsum;
    __syncthreads();

    double wiou_term = 0.0;
    if (tid < 64) {
        int bb = tid;
        double it = 0.0, ut = 0.0;
        for (int j = 0; j < BPI; ++j) {
            it += partials[(size_t)(bb * BPI + j) * 3 + 1];
            ut += partials[(size_t)(bb * BPI + j) * 3 + 2];
        }
        wiou_term = 1.0 - (it + 1.0) / (ut - it + 1.0);
    }
    if (wv == 0) {
        #pragma unroll
        for (int off = 32; off; off >>= 1) wiou_term += __shfl_down(wiou_term, off, 64);
    }
    if (tid == 0) {
        double wbce = (redbce[0] + redbce[1] + redbce[2] + redbce[3]) / (double)NELEM;
        out[0] = (float)(wbce + wiou_term * (1.0 / 64.0));
    }
}

// ---------------------------------------------------------------------------
// Fallback path (tiny ws): recompute vertical sums in-kernel + atomics.
// ---------------------------------------------------------------------------
#define ACC_DOUBLES 129
__global__ __launch_bounds__(256) void rowpass_nows_kernel(const float* __restrict__ pred,
                                                           const float* __restrict__ mask,
                                                           double* __restrict__ acc) {
    __shared__ float vrow1[WW];
    __shared__ float red[3][4];
    int b = blockIdx.x / HH;
    int h = blockIdx.x % HH;
    int lo = h - PAD; if (lo < 0) lo = 0;
    int hi = h + PAD; if (hi > HH - 1) hi = HH - 1;
    float s0 = 0.0f, s1 = 0.0f;
    const float* mb = mask + (size_t)b * HH * WW;
    for (int y = lo; y <= hi; ++y) {
        s0 += mb[(size_t)y * WW + threadIdx.x];
        s1 += mb[(size_t)y * WW + threadIdx.x + 256];
    }
    vrow1[threadIdx.x]       = s0;
    vrow1[threadIdx.x + 256] = s1;
    __syncthreads();

    size_t base = ((size_t)b * HH + h) * WW;
    float bce_p = 0.0f, inter_p = 0.0f, uni_p = 0.0f;
    for (int w = threadIdx.x; w < WW; w += 256) {
        int wlo = w - PAD; if (wlo < 0) wlo = 0;
        int whi = w + PAD; if (whi > WW - 1) whi = WW - 1;
        float s = 0.0f;
        for (int k = wlo; k <= whi; ++k) s += vrow1[k];
        float m  = mask[base + w];
        float pr = pred[base + w];
        float weit = 1.0f + 5.0f * fabsf(s * INV_KK - m);
        float e   = expf(-fabsf(pr));
        float bce = fmaxf(pr, 0.0f) - pr * m + log1pf(e);
        float inv = 1.0f / (1.0f + e);
        float p   = (pr >= 0.0f) ? inv : e * inv;
        bce_p += bce; inter_p += p * m * weit; uni_p += (p + m) * weit;
    }
    int lane = threadIdx.x & 63, wvv = threadIdx.x >> 6;
    bce_p = wave_reduce(bce_p); inter_p = wave_reduce(inter_p); uni_p = wave_reduce(uni_p);
    if (lane == 0) { red[0][wvv] = bce_p; red[1][wvv] = inter_p; red[2][wvv] = uni_p; }
    __syncthreads();
    if (threadIdx.x == 0) {
        atomicAdd(&acc[0], (double)(red[0][0] + red[0][1] + red[0][2] + red[0][3]));
        atomicAdd(&acc[1 + b], (double)(red[1][0] + red[1][1] + red[1][2] + red[1][3]));
        atomicAdd(&acc[65 + b], (double)(red[2][0] + red[2][1] + red[2][2] + red[2][3]));
    }
}

__global__ void finalize_atomic_kernel(const double* __restrict__ acc, float* __restrict__ out) {
    int b = threadIdx.x;
    double inter = acc[1 + b];
    double uni   = acc[65 + b];
    double wiou = 1.0 - (inter + 1.0) / (uni - inter + 1.0);
    #pragma unroll
    for (int off = 32; off; off >>= 1) wiou += __shfl_down(wiou, off, 64);
    if (b == 0) {
        double wbce = acc[0] / (double)NELEM;
        out[0] = (float)(wbce + wiou * (1.0 / 64.0));
    }
}

// ---------------------------------------------------------------------------
extern "C" void kernel_launch(void* const* d_in, const int* in_sizes, int n_in,
                              void* d_out, int out_size, void* d_ws, size_t ws_size,
                              hipStream_t stream) {
    const float* pred = (const float*)d_in[0];
    const float* mask = (const float*)d_in[1];
    float* out = (float*)d_out;

    const size_t part_bytes = (size_t)NBLK * 3 * sizeof(double);   // 24 KiB

    if (ws_size >= part_bytes) {
        double* partials = (double*)d_ws;
        fused_kernel<<<NBLK, 256, 0, stream>>>(pred, mask, partials);
        finalize_kernel<<<1, 256, 0, stream>>>(partials, out);
    } else {
        double* acc = (double*)d_ws;
        hipMemsetAsync(acc, 0, ACC_DOUBLES * sizeof(double), stream);
        rowpass_nows_kernel<<<BATCH * HH, 256, 0, stream>>>(pred, mask, acc);
        finalize_atomic_kernel<<<1, 64, 0, stream>>>(acc, out);
    }
}

// Round 19
// 50.093 us; speedup vs baseline: 1.6386x; 1.0303x over previous
//
#include <hip/hip_runtime.h>
#include <math.h>

// Problem constants
#define BATCH 64
#define HH 512
#define WW 512
#define PAD 15
#define NELEM ((size_t)BATCH * HH * WW)
#define INV_KK (1.0f / 961.0f)

#define TILE_H 64              // rows per block (R19: 32 -> 64, halves init overhead)
#define NIT (TILE_H / 4)       // 16
#define BPI (HH / TILE_H)      // 8 blocks per image
#define NBLK (BATCH * BPI)     // 512 blocks -> 2 blocks/CU
#define NXCD 8

typedef float f4 __attribute__((ext_vector_type(4)));

__device__ __forceinline__ float wave_reduce(float v) {
    #pragma unroll
    for (int off = 32; off; off >>= 1) v += __shfl_down(v, off, 64);
    return v;
}

// ---------------------------------------------------------------------------
// Wave64 inclusive add-scan via DPP (gfx9/CDNA rocPRIM sequence): VALU-only,
// replaces the ds_bpermute __shfl_up chain (R16: 51.5 -> 49.5us).
// ---------------------------------------------------------------------------
__device__ __forceinline__ float dpp_scan_incl(float x) {
    float v = x;
    int t;
    t = __builtin_amdgcn_update_dpp(0, __float_as_int(v), 0x111, 0xf, 0xf, true); // row_shr:1
    v += __int_as_float(t);
    t = __builtin_amdgcn_update_dpp(0, __float_as_int(v), 0x112, 0xf, 0xf, true); // row_shr:2
    v += __int_as_float(t);
    t = __builtin_amdgcn_update_dpp(0, __float_as_int(v), 0x114, 0xf, 0xf, true); // row_shr:4
    v += __int_as_float(t);
    t = __builtin_amdgcn_update_dpp(0, __float_as_int(v), 0x118, 0xf, 0xf, true); // row_shr:8
    v += __int_as_float(t);
    t = __builtin_amdgcn_update_dpp(0, __float_as_int(v), 0x142, 0xa, 0xf, true); // row_bcast15 -> rows 1,3
    v += __int_as_float(t);
    t = __builtin_amdgcn_update_dpp(0, __float_as_int(v), 0x143, 0xc, 0xf, true); // row_bcast31 -> rows 2,3
    v += __int_as_float(t);
    return v;
}

// ---------------------------------------------------------------------------
// R16 champion structure, ONE isolated change: TILE_H 32 -> 64.
// Init amortization: 31 halo rows per 64 output rows (was per 32); half the
// chip-wide serial init phases. Cost: 512 blocks = 2 blocks/CU (8 waves/CU).
// Everything else identical: prefetch, double-buffered vrow, 1 barrier per
// 4 rows, wave-private P row, DPP scan.
// ---------------------------------------------------------------------------
__global__ __launch_bounds__(256) void fused_kernel(const float* __restrict__ pred,
                                                    const float* __restrict__ mask,
                                                    double* __restrict__ partials) {
    __shared__ float vrow[2][4][WW];   // double-buffered vertical-sum rows
    __shared__ float P[4][WW];         // per-wave private prefix rows
    __shared__ float red[3][4];

    // XCD swizzle: xcd = f%8 (HW round-robin); each XCD owns 8 whole images.
    const int f    = blockIdx.x;
    const int xcd  = f & (NXCD - 1);
    const int slot = f >> 3;               // 0..63
    const int img  = xcd * 8 + (slot >> 3);   // BPI=8 -> 8 tiles/image
    const int tile = slot & (BPI - 1);

    const int tid  = threadIdx.x;
    const int lane = tid & 63;
    const int wv   = tid >> 6;
    const int h0   = tile * TILE_H;        // block's first output row (max 448)
    const int c0   = tid;                  // producer columns
    const int c1   = tid + 256;

    const float* mb = mask + (size_t)img * HH * WW;
    const float* pb = pred + (size_t)img * HH * WW;

    // --- init rolling vertical window for row h0: rows [max(0,h0-15), min(511,h0+15)]
    float r0 = 0.0f, r1 = 0.0f;
    {
        int lo = h0 - PAD; if (lo < 0) lo = 0;
        int hi = h0 + PAD; if (hi > HH - 1) hi = HH - 1;
        for (int y = lo; y <= hi; ++y) {
            r0 += mb[(size_t)y * WW + c0];
            r1 += mb[(size_t)y * WW + c1];
        }
    }

    // Prefetched add/sub rows for the upcoming iteration (rows h+16 / h-15
    // for h = hbase..hbase+3). 16 named registers.
    float pa0, pa1, pa2, pa3, ps0, ps1, ps2, ps3;   // column c0
    float qa0, qa1, qa2, qa3, qs0, qs1, qs2, qs3;   // column c1

    #define PREFETCH(ii)                                                       \
    {                                                                          \
        const int hb = h0 + 4 * (ii);                                          \
        const int a0r = hb + 16, a1r = hb + 17, a2r = hb + 18, a3r = hb + 19;  \
        const int s0r = hb - 15, s1r = hb - 14, s2r = hb - 13, s3r = hb - 12;  \
        pa0 = (a0r < HH) ? mb[(size_t)a0r * WW + c0] : 0.0f;                   \
        pa1 = (a1r < HH) ? mb[(size_t)a1r * WW + c0] : 0.0f;                   \
        pa2 = (a2r < HH) ? mb[(size_t)a2r * WW + c0] : 0.0f;                   \
        pa3 = (a3r < HH) ? mb[(size_t)a3r * WW + c0] : 0.0f;                   \
        ps0 = (s0r >= 0) ? mb[(size_t)s0r * WW + c0] : 0.0f;                   \
        ps1 = (s1r >= 0) ? mb[(size_t)s1r * WW + c0] : 0.0f;                   \
        ps2 = (s2r >= 0) ? mb[(size_t)s2r * WW + c0] : 0.0f;                   \
        ps3 = (s3r >= 0) ? mb[(size_t)s3r * WW + c0] : 0.0f;                   \
        qa0 = (a0r < HH) ? mb[(size_t)a0r * WW + c1] : 0.0f;                   \
        qa1 = (a1r < HH) ? mb[(size_t)a1r * WW + c1] : 0.0f;                   \
        qa2 = (a2r < HH) ? mb[(size_t)a2r * WW + c1] : 0.0f;                   \
        qa3 = (a3r < HH) ? mb[(size_t)a3r * WW + c1] : 0.0f;                   \
        qs0 = (s0r >= 0) ? mb[(size_t)s0r * WW + c1] : 0.0f;                   \
        qs1 = (s1r >= 0) ? mb[(size_t)s1r * WW + c1] : 0.0f;                   \
        qs2 = (s2r >= 0) ? mb[(size_t)s2r * WW + c1] : 0.0f;                   \
        qs3 = (s3r >= 0) ? mb[(size_t)s3r * WW + c1] : 0.0f;                   \
    }

    PREFETCH(0)

    float accb = 0.0f, acci = 0.0f, accu = 0.0f;

    #pragma unroll 1   // forbid outer unroll: protects the register budget
    for (int it = 0; it < NIT; ++it) {
        const int hbase = h0 + it * 4;
        float (*vb)[WW] = vrow[it & 1];

        // --- producer: pure LDS/VALU, consumes prefetched rows ---
        vb[0][c0] = r0; vb[0][c1] = r1; r0 += pa0 - ps0; r1 += qa0 - qs0;
        vb[1][c0] = r0; vb[1][c1] = r1; r0 += pa1 - ps1; r1 += qa1 - qs1;
        vb[2][c0] = r0; vb[2][c1] = r1; r0 += pa2 - ps2; r1 += qa2 - qs2;
        vb[3][c0] = r0; vb[3][c1] = r1; r0 += pa3 - ps3; r1 += qa3 - qs3;
        __syncthreads();   // vb visible to all waves (the only barrier)

        // --- issue next iteration's loads; latency hides under scan+loss ---
        if (it + 1 < NIT) PREFETCH(it + 1)

        // --- scan: wave wv prefix-scans vb[wv] into P[wv] (wave-private) ---
        const int h = hbase + wv;
        const size_t rbase = (size_t)h * WW;

        f4 va = *(const f4*)&vb[wv][8 * lane];
        f4 vbv = *(const f4*)&vb[wv][8 * lane + 4];
        float p0 = va.x;
        float p1 = p0 + va.y;
        float p2 = p1 + va.z;
        float p3 = p2 + va.w;
        float p4 = p3 + vbv.x;
        float p5 = p4 + vbv.y;
        float p6 = p5 + vbv.z;
        float p7 = p6 + vbv.w;
        const float lanesum = p7;
        const float incl = dpp_scan_incl(lanesum);   // DPP scan (R16)
        const float excl = incl - lanesum;
        f4 Pa, Pb;
        Pa.x = excl + p0; Pa.y = excl + p1; Pa.z = excl + p2; Pa.w = excl + p3;
        Pb.x = excl + p4; Pb.y = excl + p5; Pb.z = excl + p6; Pb.w = excl + p7;
        *(f4*)&P[wv][8 * lane]     = Pa;
        *(f4*)&P[wv][8 * lane + 4] = Pb;
        // no barrier: P[wv] is wave-private (same-wave DS ordering).

        // --- loss: lane owns w = lane + 64k of row hbase+wv ---
        #pragma unroll
        for (int k = 0; k < 8; ++k) {
            const int w = lane + 64 * k;
            int hiw = w + PAD; if (hiw > WW - 1) hiw = WW - 1;
            float s = P[wv][hiw];
            if (w >= PAD + 1) s -= P[wv][w - PAD - 1];

            const float m  = mb[rbase + w];
            const float pr = pb[rbase + w];

            const float weit = 1.0f + 5.0f * fabsf(s * INV_KK - m);
            const float e    = __expf(-fabsf(pr));
            const float bce  = fmaxf(pr, 0.0f) - pr * m + __logf(1.0f + e);
            const float inv  = __builtin_amdgcn_rcpf(1.0f + e);
            const float p    = (pr >= 0.0f) ? inv : e * inv;   // sigmoid(pr)

            accb += bce;
            acci += p * m * weit;
            accu += (p + m) * weit;
        }
        // no end barrier: vrow is double-buffered (R11 safety argument).
    }
    #undef PREFETCH

    // --- block reduction ---
    accb = wave_reduce(accb);
    acci = wave_reduce(acci);
    accu = wave_reduce(accu);
    if (lane == 0) { red[0][wv] = accb; red[1][wv] = acci; red[2][wv] = accu; }
    __syncthreads();
    if (tid == 0) {
        double bt = (double)red[0][0] + red[0][1] + red[0][2] + red[0][3];
        double it2 = (double)red[1][0] + red[1][1] + red[1][2] + red[1][3];
        double ut = (double)red[2][0] + red[2][1] + red[2][2] + red[2][3];
        const size_t pidx = (size_t)img * BPI + tile;   // un-swizzled index
        partials[pidx * 3 + 0] = bt;
        partials[pidx * 3 + 1] = it2;
        partials[pidx * 3 + 2] = ut;
    }
}

// ---------------------------------------------------------------------------
// Finalize from per-block partials (indexed img*BPI + tile), NBLK = 512.
// ---------------------------------------------------------------------------
__global__ __launch_bounds__(256) void finalize_kernel(const double* __restrict__ partials,
                                                       float* __restrict__ out) {
    __shared__ double redbce[4];
    int tid = threadIdx.x, lane = tid & 63, wv = tid >> 6;

    double bsum = 0.0;
    for (int i = tid; i < NBLK; i += 256) bsum += partials[(size_t)i * 3 + 0];
    #pragma unroll
    for (int off = 32; off; off >>= 1) bsum += __shfl_down(bsum, off, 64);
    if (lane == 0) redbce[wv] = bsum;
    __syncthreads();

    double wiou_term = 0.0;
    if (tid < 64) {
        int bb = tid;
        double it = 0.0, ut = 0.0;
        for (int j = 0; j < BPI; ++j) {
            it += partials[(size_t)(bb * BPI + j) * 3 + 1];
            ut += partials[(size_t)(bb * BPI + j) * 3 + 2];
        }
        wiou_term = 1.0 - (it + 1.0) / (ut - it + 1.0);
    }
    if (wv == 0) {
        #pragma unroll
        for (int off = 32; off; off >>= 1) wiou_term += __shfl_down(wiou_term, off, 64);
    }
    if (tid == 0) {
        double wbce = (redbce[0] + redbce[1] + redbce[2] + redbce[3]) / (double)NELEM;
        out[0] = (float)(wbce + wiou_term * (1.0 / 64.0));
    }
}

// ---------------------------------------------------------------------------
// Fallback path (tiny ws): recompute vertical sums in-kernel + atomics.
// ---------------------------------------------------------------------------
#define ACC_DOUBLES 129
__global__ __launch_bounds__(256) void rowpass_nows_kernel(const float* __restrict__ pred,
                                                           const float* __restrict__ mask,
                                                           double* __restrict__ acc) {
    __shared__ float vrow1[WW];
    __shared__ float red[3][4];
    int b = blockIdx.x / HH;
    int h = blockIdx.x % HH;
    int lo = h - PAD; if (lo < 0) lo = 0;
    int hi = h + PAD; if (hi > HH - 1) hi = HH - 1;
    float s0 = 0.0f, s1 = 0.0f;
    const float* mb = mask + (size_t)b * HH * WW;
    for (int y = lo; y <= hi; ++y) {
        s0 += mb[(size_t)y * WW + threadIdx.x];
        s1 += mb[(size_t)y * WW + threadIdx.x + 256];
    }
    vrow1[threadIdx.x]       = s0;
    vrow1[threadIdx.x + 256] = s1;
    __syncthreads();

    size_t base = ((size_t)b * HH + h) * WW;
    float bce_p = 0.0f, inter_p = 0.0f, uni_p = 0.0f;
    for (int w = threadIdx.x; w < WW; w += 256) {
        int wlo = w - PAD; if (wlo < 0) wlo = 0;
        int whi = w + PAD; if (whi > WW - 1) whi = WW - 1;
        float s = 0.0f;
        for (int k = wlo; k <= whi; ++k) s += vrow1[k];
        float m  = mask[base + w];
        float pr = pred[base + w];
        float weit = 1.0f + 5.0f * fabsf(s * INV_KK - m);
        float e   = expf(-fabsf(pr));
        float bce = fmaxf(pr, 0.0f) - pr * m + log1pf(e);
        float inv = 1.0f / (1.0f + e);
        float p   = (pr >= 0.0f) ? inv : e * inv;
        bce_p += bce; inter_p += p * m * weit; uni_p += (p + m) * weit;
    }
    int lane = threadIdx.x & 63, wvv = threadIdx.x >> 6;
    bce_p = wave_reduce(bce_p); inter_p = wave_reduce(inter_p); uni_p = wave_reduce(uni_p);
    if (lane == 0) { red[0][wvv] = bce_p; red[1][wvv] = inter_p; red[2][wvv] = uni_p; }
    __syncthreads();
    if (threadIdx.x == 0) {
        atomicAdd(&acc[0], (double)(red[0][0] + red[0][1] + red[0][2] + red[0][3]));
        atomicAdd(&acc[1 + b], (double)(red[1][0] + red[1][1] + red[1][2] + red[1][3]));
        atomicAdd(&acc[65 + b], (double)(red[2][0] + red[2][1] + red[2][2] + red[2][3]));
    }
}

__global__ void finalize_atomic_kernel(const double* __restrict__ acc, float* __restrict__ out) {
    int b = threadIdx.x;
    double inter = acc[1 + b];
    double uni   = acc[65 + b];
    double wiou = 1.0 - (inter + 1.0) / (uni - inter + 1.0);
    #pragma unroll
    for (int off = 32; off; off >>= 1) wiou += __shfl_down(wiou, off, 64);
    if (b == 0) {
        double wbce = acc[0] / (double)NELEM;
        out[0] = (float)(wbce + wiou * (1.0 / 64.0));
    }
}

// ---------------------------------------------------------------------------
extern "C" void kernel_launch(void* const* d_in, const int* in_sizes, int n_in,
                              void* d_out, int out_size, void* d_ws, size_t ws_size,
                              hipStream_t stream) {
    const float* pred = (const float*)d_in[0];
    const float* mask = (const float*)d_in[1];
    float* out = (float*)d_out;

    const size_t part_bytes = (size_t)NBLK * 3 * sizeof(double);   // 12 KiB

    if (ws_size >= part_bytes) {
        double* partials = (double*)d_ws;
        fused_kernel<<<NBLK, 256, 0, stream>>>(pred, mask, partials);
        finalize_kernel<<<1, 256, 0, stream>>>(partials, out);
    } else {
        double* acc = (double*)d_ws;
        hipMemsetAsync(acc, 0, ACC_DOUBLES * sizeof(double), stream);
        rowpass_nows_kernel<<<BATCH * HH, 256, 0, stream>>>(pred, mask, acc);
        finalize_atomic_kernel<<<1, 64, 0, stream>>>(acc, out);
    }
}